// Round 6
// baseline (157241.907 us; speedup 1.0000x reference)
//
#include <hip/hip_runtime.h>
#include <cstdint>

#define T_LEN 16384
#define X_DIM 256
#define H_DIM 1024
#define NREP  8                    // h-buffer replicas (slice spreading)
#define SLOT_U32 1024              // col c lives at dword c (linear, proven r2)
#define REP_U32  (2 * SLOT_U32)    // ping-pong slots per replica
#define FLAG_OFF (NREP * REP_U32)  // 16384 dwords = 64 KB

typedef unsigned int u32;
typedef u32   u32x4 __attribute__((ext_vector_type(4)));
typedef float f32x4 __attribute__((ext_vector_type(4)));

// ---------------------------------------------------------------------------
// Device-scope coherent ops. sc0 sc1 -> MALL is the coherence point (per-XCD
// L2s are NOT cross-coherent; r3 proved sc0-only visibility is eviction-
// timing-dependent). Every published dword self-validates via a 2-bit step
// tag in its mantissa LSBs -> only 4 B atomicity required.
// r4/r5 LESSON (filed): in-flight VMEM destination registers must NEVER
// cross an inline-asm boundary as C++ SSA values -- the register allocator
// may copy a not-yet-landed register; the load then lands in the original
// while the check spins on the stale copy forever. Hence the whole poll
// loop below lives in ONE asm block.
// ---------------------------------------------------------------------------
__device__ __forceinline__ void coh_store4(u32* p, u32x4 v) {
  asm volatile("global_store_dwordx4 %0, %1, off sc0 sc1" :: "v"(p), "v"(v) : "memory");
}
__device__ __forceinline__ void coh_store1(u32* p, u32 v) {
  asm volatile("global_store_dword %0, %1, off sc0 sc1" :: "v"(p), "v"(v) : "memory");
}
__device__ __forceinline__ u32 coh_load1(const u32* p) {
  u32 v;
  asm volatile("global_load_dword %0, %1, off sc0 sc1\n\ts_waitcnt vmcnt(0)"
               : "=v"(v) : "v"(p) : "memory");
  return v;
}

__device__ __forceinline__ float fast_tanh(float x) {
  x = fminf(9.0f, fmaxf(-9.0f, x));
  const float e = __builtin_amdgcn_exp2f(x * 2.8853900817779268f); // 2*log2(e)
  return (e - 1.0f) * __builtin_amdgcn_rcpf(e + 1.0f);
}

// ---- twin-buffer poll: all liveness inside one asm block -------------------
// Two sets (A,B) of 16 scalar dword loads of this lane's 64 B group.
// vmcnt retires in issue order: with 32 outstanding, vmcnt(16) == "the
// older set has fully landed". Whole-wave re-poll (no exec dropout):
// re-reading an accepted group returns the same h(t) (nothing overwrites
// those dwords until the next same-slot publish, which transitively
// requires THIS wave's own publish). Accept-B path waits vmcnt(0) BEFORE
// copying B->A so the in-flight A-reissue cannot land on top of the copy.
// In-asm SGPR deadman: 2^22 misses (~<=0.5 s worst; expected ~70k).
#define LD_SET(q)                                                        \
  "global_load_dword %[" #q "0], %[gp], off sc0 sc1\n\t"                 \
  "global_load_dword %[" #q "1], %[gp], off offset:4 sc0 sc1\n\t"        \
  "global_load_dword %[" #q "2], %[gp], off offset:8 sc0 sc1\n\t"        \
  "global_load_dword %[" #q "3], %[gp], off offset:12 sc0 sc1\n\t"       \
  "global_load_dword %[" #q "4], %[gp], off offset:16 sc0 sc1\n\t"       \
  "global_load_dword %[" #q "5], %[gp], off offset:20 sc0 sc1\n\t"       \
  "global_load_dword %[" #q "6], %[gp], off offset:24 sc0 sc1\n\t"       \
  "global_load_dword %[" #q "7], %[gp], off offset:28 sc0 sc1\n\t"       \
  "global_load_dword %[" #q "8], %[gp], off offset:32 sc0 sc1\n\t"       \
  "global_load_dword %[" #q "9], %[gp], off offset:36 sc0 sc1\n\t"       \
  "global_load_dword %[" #q "10], %[gp], off offset:40 sc0 sc1\n\t"      \
  "global_load_dword %[" #q "11], %[gp], off offset:44 sc0 sc1\n\t"      \
  "global_load_dword %[" #q "12], %[gp], off offset:48 sc0 sc1\n\t"      \
  "global_load_dword %[" #q "13], %[gp], off offset:52 sc0 sc1\n\t"      \
  "global_load_dword %[" #q "14], %[gp], off offset:56 sc0 sc1\n\t"      \
  "global_load_dword %[" #q "15], %[gp], off offset:60 sc0 sc1\n\t"

#define CHK_PAIR(q, i)                                                   \
  "v_xor_b32 %[u], %[stag], %[" #q #i "]\n\t"                            \
  "v_or_b32 %[t], %[t], %[u]\n\t"

#define CHK_SET(q)                                                       \
  "v_xor_b32 %[t], %[stag], %[" #q "0]\n\t"                              \
  CHK_PAIR(q, 1) CHK_PAIR(q, 2) CHK_PAIR(q, 3) CHK_PAIR(q, 4)            \
  CHK_PAIR(q, 5) CHK_PAIR(q, 6) CHK_PAIR(q, 7) CHK_PAIR(q, 8)            \
  CHK_PAIR(q, 9) CHK_PAIR(q, 10) CHK_PAIR(q, 11) CHK_PAIR(q, 12)         \
  CHK_PAIR(q, 13) CHK_PAIR(q, 14) CHK_PAIR(q, 15)                        \
  "v_and_b32 %[t], 3, %[t]\n\t"                                          \
  "v_cmp_ne_u32 vcc, 0, %[t]\n\t"

// xor1 / xor2 within each quad via DPP quad_perm (pure VALU).
__device__ __forceinline__ float dpp_xor1(float x) {  // quad_perm [1,0,3,2]
  return __int_as_float(__builtin_amdgcn_update_dpp(0, __float_as_int(x),
                                                    0xB1, 0xF, 0xF, false));
}
__device__ __forceinline__ float dpp_xor2(float x) {  // quad_perm [2,3,0,1]
  return __int_as_float(__builtin_amdgcn_update_dpp(0, __float_as_int(x),
                                                    0x4E, 0xF, 0xF, false));
}

// ---------------------------------------------------------------------------
// Kernel 0: seed slot 0 of every replica with h0 (tag 0) and zero the filler
// done-flag. Poison 0xAAAAAAAA has tag LSBs 0b10, never matching slot0 tags
// {0,2} (overwritten here) nor slot1's first expected tag 1.
// ---------------------------------------------------------------------------
__global__ void hinit(const float* __restrict__ h0, u32* __restrict__ ws) {
  const int i = threadIdx.x;              // 256 threads x 4 cols
  const f32x4 h = *(const f32x4*)(h0 + i * 4);
  u32x4 v;
  v.x = __float_as_uint(h[0]) & ~3u;
  v.y = __float_as_uint(h[1]) & ~3u;
  v.z = __float_as_uint(h[2]) & ~3u;
  v.w = __float_as_uint(h[3]) & ~3u;
  const int idx = i * 4;                  // linear layout, 16 B aligned
#pragma unroll
  for (int rep = 0; rep < NREP; ++rep)
    coh_store4(ws + (size_t)rep * REP_U32 + idx, v);
  if (i < 2) coh_store1(ws + FLAG_OFF + i, 0u);  // done flag + spare
}

// ---------------------------------------------------------------------------
// Kernel 1: Bx_c = x @ B^T + c into d_out. Unchanged (proven).
// ---------------------------------------------------------------------------
__global__ __launch_bounds__(256) void gemm_bx(const float* __restrict__ x,
                                               const float* __restrict__ Bm,
                                               const float* __restrict__ c,
                                               float* __restrict__ out) {
  __shared__ float xs[64][68];
  __shared__ float bs[64][68];

  const int tid = threadIdx.x;
  const int t0  = blockIdx.x * 64;
  const int h0  = blockIdx.y * 64;
  const int lr  = tid >> 4;
  const int lc  = tid & 15;

  float acc[4][4] = {};

  for (int kb = 0; kb < X_DIM; kb += 64) {
    const int kk  = (tid & 15) * 4;
    const int tt0 = tid >> 4;
#pragma unroll
    for (int i = 0; i < 4; ++i) {
      const int tt = tt0 + i * 16;
      const f32x4 xv = *(const f32x4*)(x  + (size_t)(t0 + tt) * X_DIM + kb + kk);
      const f32x4 bv = *(const f32x4*)(Bm + (size_t)(h0 + tt) * X_DIM + kb + kk);
#pragma unroll
      for (int q = 0; q < 4; ++q) {
        xs[kk + q][tt] = xv[q];
        bs[kk + q][tt] = bv[q];
      }
    }
    __syncthreads();

#pragma unroll 8
    for (int k = 0; k < 64; ++k) {
      const f32x4 xv = *(const f32x4*)&xs[k][lr * 4];
      const f32x4 bv = *(const f32x4*)&bs[k][lc * 4];
#pragma unroll
      for (int i = 0; i < 4; ++i)
#pragma unroll
        for (int j = 0; j < 4; ++j)
          acc[i][j] = fmaf(xv[i], bv[j], acc[i][j]);
    }
    __syncthreads();
  }

  const f32x4 cv = *(const f32x4*)(c + h0 + lc * 4);
#pragma unroll
  for (int i = 0; i < 4; ++i) {
    f32x4 o;
#pragma unroll
    for (int j = 0; j < 4; ++j) o[j] = acc[i][j] + cv[j];
    *(f32x4*)(out + (size_t)(t0 + lr * 4 + i) * H_DIM + h0 + lc * 4) = o;
  }
}

// ---------------------------------------------------------------------------
// Kernel 2: 256 blocks. Blocks 0-63 = scan workers (r2-proven geometry:
// 4 waves/block, wave owns 4 rows, lane l polls h[16l..16l+15] from its
// replica into registers; publish lanes<32, one instr). Changes vs r2:
//  (1) twin-buffer poll, ALL inside one asm block (see LD_SET/CHK_SET);
//  (2) transposed reduce: 2 DPP quad_perm folds + 4 shfl_xor -> lane ends
//      holding its OWN row's total (replaces 4x full all-reduce + select).
// Skew proof unchanged: publishing t+1 requires full h(t) validated (all 64
// groups, one per lane) -> every wave finished t-1 -> the (slot,tag) being
// overwritten has no remaining readers. The asm block's entry/exit
// vmcnt(0) preserves the per-step drain that orders same-dword publishes
// across the 4-step (slot,tag) reuse period.
// Blocks 64-255 = DVFS fillers (unchanged, hard-capped).
// ---------------------------------------------------------------------------
__global__ __launch_bounds__(256) void rnn_scan(const float* __restrict__ A_raw,
                                                float* __restrict__ out,
                                                u32* __restrict__ ws) {
  const int tid = threadIdx.x;

  if (blockIdx.x >= 64) {
    // ---- filler: keep the DPM governor at high clock ----
    const u32* flag = ws + FLAG_OFF;
    float f0 = 0.f, f1 = 0.f, f2 = 0.f, f3 = 0.f;
    float f4 = 0.f, f5 = 0.f, f6 = 0.f, f7 = 0.f;
    const float m = 1.0000001f, ad = 1e-9f;
    for (int outer = 0; outer < 32768; ++outer) {   // hard cap ~56 ms @2.4GHz
      if (coh_load1(flag) != 0u) break;
      for (int i = 0; i < 256; ++i) {               // ~4096 cyc of VALU burn
        f0 = fmaf(f0, m, ad); f1 = fmaf(f1, m, ad);
        f2 = fmaf(f2, m, ad); f3 = fmaf(f3, m, ad);
        f4 = fmaf(f4, m, ad); f5 = fmaf(f5, m, ad);
        f6 = fmaf(f6, m, ad); f7 = fmaf(f7, m, ad);
      }
    }
    if (f0 + f1 + f2 + f3 + f4 + f5 + f6 + f7 == 123456.789f && tid == 0)
      coh_store1(ws + FLAG_OFF + 1, 1u);            // DCE guard, never true
    return;
  }

  // ---- worker wave (r2 geometry) ----
  const int lane    = tid & 63;
  const int wv      = tid >> 6;
  const int wg      = blockIdx.x;
  const int gw      = wg * 4 + wv;      // global wave id 0..255
  const int rowbase = gw * 4;
  const int r       = lane & 3;
  const int row     = rowbase + r;      // this lane's output row (lanes mod 4)

  // A fragment: a[rr][k] = 0.1*A_raw[rowbase+rr][16*lane+k] + 0.9*(col==row).
  float a[4][16];
#pragma unroll
  for (int rr = 0; rr < 4; ++rr) {
#pragma unroll
    for (int k4 = 0; k4 < 4; ++k4) {
      const f32x4 v = *(const f32x4*)(A_raw + (size_t)(rowbase + rr) * H_DIM +
                                      lane * 16 + k4 * 4);
#pragma unroll
      for (int q = 0; q < 4; ++q) {
        const int col = lane * 16 + k4 * 4 + q;
        a[rr][k4 * 4 + q] = 0.1f * v[q] + (col == rowbase + rr ? 0.9f : 0.0f);
      }
    }
  }

  u32* hbuf = ws;
  const u32* ppoll0 = hbuf + (size_t)(gw & (NREP - 1)) * REP_U32 + 16 * lane;
  u32* pub = hbuf + (size_t)(lane >> 2) * REP_U32 + rowbase + r;  // lanes<32

  // 2-deep bx prefetch: out[t] rows are only overwritten by THIS wave at
  // step t -> reading out[t+2] at step t is read-before-write, same wave.
  float bx_val = out[(size_t)0 * H_DIM + row];
  float bx_n1  = out[(size_t)1 * H_DIM + row];

  for (int t = 0; t < T_LEN; ++t) {
    const u32 tag = (u32)(t & 3);
    const u32* p  = ppoll0 + (t & 1) * SLOT_U32;

    u32 A[16], B[16], tmp1, tmp2, tmo;
    u32 sdead;
    asm volatile(
        // entry drain: prior publish/out/bx VMEM retired (per-step invariant)
        "s_waitcnt vmcnt(0)\n\t"
        "s_mov_b32 %[sd], 0x400000\n\t"      // deadman: 2^22 misses
        "v_mov_b32 %[to], 0\n\t"
        LD_SET(a)                             // issue set A (16 dwords)
        LD_SET(b)                             // issue set B
        "Lp%=:\n\t"
        "s_waitcnt vmcnt(16)\n\t"            // set A landed (FIFO)
        CHK_SET(a)                            // vcc = per-lane mismatch
        "s_cbranch_vccz La%=\n\t"            // all 64 lanes tagged -> accept A
        "s_sub_u32 %[sd], %[sd], 1\n\t"
        "s_cbranch_scc1 Lt%=\n\t"            // borrow -> timeout
        LD_SET(a)                             // re-issue A
        "s_waitcnt vmcnt(16)\n\t"            // set B landed
        CHK_SET(b)
        "s_cbranch_vccz Lb%=\n\t"
        "s_sub_u32 %[sd], %[sd], 1\n\t"
        "s_cbranch_scc1 Lt%=\n\t"
        LD_SET(b)                             // re-issue B
        "s_branch Lp%=\n\t"
        "Lb%=:\n\t"
        "s_waitcnt vmcnt(0)\n\t"             // let A's in-flight reissue land
        "v_mov_b32 %[a0], %[b0]\n\t"         // ...so this copy can't be clobbered
        "v_mov_b32 %[a1], %[b1]\n\t"
        "v_mov_b32 %[a2], %[b2]\n\t"
        "v_mov_b32 %[a3], %[b3]\n\t"
        "v_mov_b32 %[a4], %[b4]\n\t"
        "v_mov_b32 %[a5], %[b5]\n\t"
        "v_mov_b32 %[a6], %[b6]\n\t"
        "v_mov_b32 %[a7], %[b7]\n\t"
        "v_mov_b32 %[a8], %[b8]\n\t"
        "v_mov_b32 %[a9], %[b9]\n\t"
        "v_mov_b32 %[a10], %[b10]\n\t"
        "v_mov_b32 %[a11], %[b11]\n\t"
        "v_mov_b32 %[a12], %[b12]\n\t"
        "v_mov_b32 %[a13], %[b13]\n\t"
        "v_mov_b32 %[a14], %[b14]\n\t"
        "v_mov_b32 %[a15], %[b15]\n\t"
        "s_branch Le%=\n\t"
        "Lt%=:\n\t"
        "v_mov_b32 %[to], 1\n\t"
        "La%=:\n\t"
        "Le%=:\n\t"
        "s_waitcnt vmcnt(0)\n\t"             // drain stragglers (other set)
        : [a0]"=&v"(A[0]), [a1]"=&v"(A[1]), [a2]"=&v"(A[2]), [a3]"=&v"(A[3]),
          [a4]"=&v"(A[4]), [a5]"=&v"(A[5]), [a6]"=&v"(A[6]), [a7]"=&v"(A[7]),
          [a8]"=&v"(A[8]), [a9]"=&v"(A[9]), [a10]"=&v"(A[10]), [a11]"=&v"(A[11]),
          [a12]"=&v"(A[12]), [a13]"=&v"(A[13]), [a14]"=&v"(A[14]), [a15]"=&v"(A[15]),
          [b0]"=&v"(B[0]), [b1]"=&v"(B[1]), [b2]"=&v"(B[2]), [b3]"=&v"(B[3]),
          [b4]"=&v"(B[4]), [b5]"=&v"(B[5]), [b6]"=&v"(B[6]), [b7]"=&v"(B[7]),
          [b8]"=&v"(B[8]), [b9]"=&v"(B[9]), [b10]"=&v"(B[10]), [b11]"=&v"(B[11]),
          [b12]"=&v"(B[12]), [b13]"=&v"(B[13]), [b14]"=&v"(B[14]), [b15]"=&v"(B[15]),
          [t]"=&v"(tmp1), [u]"=&v"(tmp2), [to]"=&v"(tmo), [sd]"=&s"(sdead)
        : [gp]"v"(p), [stag]"s"(tag)
        : "vcc", "scc", "memory");

    if (__any(tmo != 0u)) {
      if (lane == 0) coh_store1(ws + FLAG_OFF, 1u);  // fail fast, release fillers
      return;
    }

    // Issue bx(t+2) now; ~2 full step periods to cover HBM latency.
    const int tn2 = (t + 2 < T_LEN) ? t + 2 : t;
    const float bx_n2 = out[(size_t)tn2 * H_DIM + row];

    // Partial dots straight from poll registers (tag bits left in mantissa,
    // rel err <= 2^-22 -- same as proven version).
    float hv[16];
#pragma unroll
    for (int k = 0; k < 16; ++k) hv[k] = __uint_as_float(A[k]);

    float ac0 = 0.f, ac1 = 0.f, ac2 = 0.f, ac3 = 0.f;
#pragma unroll
    for (int k = 0; k < 16; ++k) {
      ac0 = fmaf(a[0][k], hv[k], ac0);
      ac1 = fmaf(a[1][k], hv[k], ac1);
      ac2 = fmaf(a[2][k], hv[k], ac2);
      ac3 = fmaf(a[3][k], hv[k], ac3);
    }

    // Transposed reduce: fold 4 values -> 1 per lane (2 DPP quad_perm
    // steps), then 4 shfl_xor across quads. Lane l ends holding the full
    // 64-lane sum of ac_{l&3} == its own row's dot product.
    const float lo01 = (lane & 1) ? ac1 : ac0;
    const float ot01 = (lane & 1) ? ac0 : ac1;
    const float lo23 = (lane & 1) ? ac3 : ac2;
    const float ot23 = (lane & 1) ? ac2 : ac3;
    const float p01  = lo01 + dpp_xor1(ot01);
    const float p23  = lo23 + dpp_xor1(ot23);
    const float keep = (lane & 2) ? p23 : p01;
    const float give = (lane & 2) ? p01 : p23;
    float x = keep + dpp_xor2(give);
    x += __shfl_xor(x, 4, 64);
    x += __shfl_xor(x, 8, 64);
    x += __shfl_xor(x, 16, 64);
    x += __shfl_xor(x, 32, 64);

    const float v = fast_tanh(x + bx_val);
    bx_val = bx_n1;
    bx_n1  = bx_n2;

    const u32 nt = (u32)((t + 1) & 3);
    if (lane < 4 * NREP) {
      // lanes 0..31: publish to replica lane>>2, row-class lane&3.
      coh_store1(pub + (size_t)((t + 1) & 1) * SLOT_U32,
                 (__float_as_uint(v) & ~3u) | nt);
    } else if (lane < 4 * NREP + 4) {
      // lanes 32..35: clean output write (bx already consumed this step).
      out[(size_t)t * H_DIM + row] = v;
    }
  }

  if (gw == 0 && lane == 0) coh_store1(ws + FLAG_OFF, 1u);  // release fillers
}

// ---------------------------------------------------------------------------
extern "C" void kernel_launch(void* const* d_in, const int* in_sizes, int n_in,
                              void* d_out, int out_size, void* d_ws, size_t ws_size,
                              hipStream_t stream) {
  const float* x    = (const float*)d_in[0];  // (T, X)
  const float* h0   = (const float*)d_in[1];  // (H,)
  const float* Araw = (const float*)d_in[2];  // (H, H)
  const float* B    = (const float*)d_in[3];  // (H, X)
  const float* c    = (const float*)d_in[4];  // (H,)
  float* out = (float*)d_out;                 // (T, H)
  u32* ws    = (u32*)d_ws;                    // 64 KB hbuf + flag dwords

  hinit<<<1, 256, 0, stream>>>(h0, ws);
  dim3 g(T_LEN / 64, H_DIM / 64);
  gemm_bx<<<g, 256, 0, stream>>>(x, B, c, out);
  rnn_scan<<<256, 256, 0, stream>>>(Araw, out, ws);
}

// Round 7
// 91369.659 us; speedup vs baseline: 1.7209x; 1.7209x over previous
//
#include <hip/hip_runtime.h>
#include <cstdint>

#define T_LEN 16384
#define X_DIM 256
#define H_DIM 1024
#define NREP  8                    // h-buffer replicas (slice spreading)
#define SLOT_U32 1024              // col c lives at dword c (linear, proven r2)
#define REP_U32  (2 * SLOT_U32)    // ping-pong slots per replica
#define FLAG_OFF (NREP * REP_U32)  // 16384 dwords = 64 KB

typedef unsigned int u32;
typedef u32   u32x4 __attribute__((ext_vector_type(4)));
typedef float f32x4 __attribute__((ext_vector_type(4)));

// ---------------------------------------------------------------------------
// Device-scope coherent ops. sc0 sc1 -> MALL is the coherence point (per-XCD
// L2s are NOT cross-coherent; r3: sc0-only visibility is eviction-timing-
// dependent). Every published dword self-validates via a 2-bit step tag in
// its mantissa LSBs -> only 4 B atomicity required.
// r4/r5 LESSON: in-flight VMEM destination registers must never cross an
// inline-asm boundary as C++ SSA values (regalloc copies a not-yet-landed
// register; the load lands in the original; the check spins forever).
// r6 LESSON: poll aggressiveness is a shared-fabric resource -- 16 scalar
// loads/set unthrottled saturated the MALL request path (7x slowdown).
// This version: 4 sentinel dwords + 4 speculative dwordx4 per set, twin-
// buffered, s_sleep-throttled, all in ONE asm block; C++ re-verifies all 16
// tags after landing and falls back to the r2-proven serial poll on any
// mismatch. No new atomicity assumptions.
// ---------------------------------------------------------------------------
__device__ __forceinline__ void coh_store4(u32* p, u32x4 v) {
  asm volatile("global_store_dwordx4 %0, %1, off sc0 sc1" :: "v"(p), "v"(v) : "memory");
}
__device__ __forceinline__ void coh_store1(u32* p, u32 v) {
  asm volatile("global_store_dword %0, %1, off sc0 sc1" :: "v"(p), "v"(v) : "memory");
}
__device__ __forceinline__ u32 coh_load1(const u32* p) {
  u32 v;
  asm volatile("global_load_dword %0, %1, off sc0 sc1\n\ts_waitcnt vmcnt(0)"
               : "=v"(v) : "v"(p) : "memory");
  return v;
}
// r2-proven serial full poll iteration: 4 dwordx4 + vmcnt(0), values landed
// before the asm exits (safe to use from C++ each iteration).
__device__ __forceinline__ void poll_group(const u32* p, u32x4& a, u32x4& b,
                                           u32x4& c, u32x4& d) {
  asm volatile(
      "global_load_dwordx4 %0, %4, off sc0 sc1\n\t"
      "global_load_dwordx4 %1, %4, off offset:16 sc0 sc1\n\t"
      "global_load_dwordx4 %2, %4, off offset:32 sc0 sc1\n\t"
      "global_load_dwordx4 %3, %4, off offset:48 sc0 sc1\n\t"
      "s_waitcnt vmcnt(0)"
      : "=&v"(a), "=&v"(b), "=&v"(c), "=&v"(d) : "v"(p) : "memory");
}

__device__ __forceinline__ u32 tagchk(const u32x4& a, const u32x4& b,
                                      const u32x4& c, const u32x4& d, u32 tag) {
  const u32 m = (a.x ^ tag) | (a.y ^ tag) | (a.z ^ tag) | (a.w ^ tag)
              | (b.x ^ tag) | (b.y ^ tag) | (b.z ^ tag) | (b.w ^ tag)
              | (c.x ^ tag) | (c.y ^ tag) | (c.z ^ tag) | (c.w ^ tag)
              | (d.x ^ tag) | (d.y ^ tag) | (d.z ^ tag) | (d.w ^ tag);
  return m & 3u;
}

__device__ __forceinline__ float fast_tanh(float x) {
  x = fminf(9.0f, fmaxf(-9.0f, x));
  const float e = __builtin_amdgcn_exp2f(x * 2.8853900817779268f); // 2*log2(e)
  return (e - 1.0f) * __builtin_amdgcn_rcpf(e + 1.0f);
}

// ---- sentinel + speculative-full twin poll (one asm block) -----------------
// Sentinels = group dwords 0,4,8,12 (offsets 0/16/32/48) = one row from each
// of the 4 waves that publish into this lane's group -> sentinel pass means
// all 4 publishers have stored step t. Full dwordx4 loads issued in the same
// set sample ~the same memory state; tags re-verified in C++ after landing.
#define ISSUE_SET(s0, s1, s2, s3, f0, f1, f2, f3)                        \
  "global_load_dword %[" #s0 "], %[gp], off sc0 sc1\n\t"                 \
  "global_load_dword %[" #s1 "], %[gp], off offset:16 sc0 sc1\n\t"       \
  "global_load_dword %[" #s2 "], %[gp], off offset:32 sc0 sc1\n\t"       \
  "global_load_dword %[" #s3 "], %[gp], off offset:48 sc0 sc1\n\t"       \
  "global_load_dwordx4 %[" #f0 "], %[gp], off sc0 sc1\n\t"               \
  "global_load_dwordx4 %[" #f1 "], %[gp], off offset:16 sc0 sc1\n\t"     \
  "global_load_dwordx4 %[" #f2 "], %[gp], off offset:32 sc0 sc1\n\t"     \
  "global_load_dwordx4 %[" #f3 "], %[gp], off offset:48 sc0 sc1\n\t"

#define CHK_SENT(s0, s1, s2, s3)                                         \
  "v_xor_b32 %[t], %[stag], %[" #s0 "]\n\t"                              \
  "v_xor_b32 %[u], %[stag], %[" #s1 "]\n\t"                              \
  "v_or_b32 %[t], %[t], %[u]\n\t"                                        \
  "v_xor_b32 %[u], %[stag], %[" #s2 "]\n\t"                              \
  "v_or_b32 %[t], %[t], %[u]\n\t"                                        \
  "v_xor_b32 %[u], %[stag], %[" #s3 "]\n\t"                              \
  "v_or_b32 %[t], %[t], %[u]\n\t"                                        \
  "v_and_b32 %[t], 3, %[t]\n\t"                                          \
  "v_cmp_ne_u32 vcc, 0, %[t]\n\t"

// xor1 / xor2 within each quad via DPP quad_perm (pure VALU). [r6 HW-proven]
__device__ __forceinline__ float dpp_xor1(float x) {  // quad_perm [1,0,3,2]
  return __int_as_float(__builtin_amdgcn_update_dpp(0, __float_as_int(x),
                                                    0xB1, 0xF, 0xF, false));
}
__device__ __forceinline__ float dpp_xor2(float x) {  // quad_perm [2,3,0,1]
  return __int_as_float(__builtin_amdgcn_update_dpp(0, __float_as_int(x),
                                                    0x4E, 0xF, 0xF, false));
}

// ---------------------------------------------------------------------------
// Kernel 0: seed slot 0 of every replica with h0 (tag 0) and zero the filler
// done-flag. Poison 0xAAAAAAAA has tag LSBs 0b10, never matching slot0 tags
// {0,2} (overwritten here) nor slot1's first expected tag 1.
// ---------------------------------------------------------------------------
__global__ void hinit(const float* __restrict__ h0, u32* __restrict__ ws) {
  const int i = threadIdx.x;              // 256 threads x 4 cols
  const f32x4 h = *(const f32x4*)(h0 + i * 4);
  u32x4 v;
  v.x = __float_as_uint(h[0]) & ~3u;
  v.y = __float_as_uint(h[1]) & ~3u;
  v.z = __float_as_uint(h[2]) & ~3u;
  v.w = __float_as_uint(h[3]) & ~3u;
  const int idx = i * 4;                  // linear layout, 16 B aligned
#pragma unroll
  for (int rep = 0; rep < NREP; ++rep)
    coh_store4(ws + (size_t)rep * REP_U32 + idx, v);
  if (i < 2) coh_store1(ws + FLAG_OFF + i, 0u);  // done flag + spare
}

// ---------------------------------------------------------------------------
// Kernel 1: Bx_c = x @ B^T + c into d_out. Unchanged (proven).
// ---------------------------------------------------------------------------
__global__ __launch_bounds__(256) void gemm_bx(const float* __restrict__ x,
                                               const float* __restrict__ Bm,
                                               const float* __restrict__ c,
                                               float* __restrict__ out) {
  __shared__ float xs[64][68];
  __shared__ float bs[64][68];

  const int tid = threadIdx.x;
  const int t0  = blockIdx.x * 64;
  const int h0  = blockIdx.y * 64;
  const int lr  = tid >> 4;
  const int lc  = tid & 15;

  float acc[4][4] = {};

  for (int kb = 0; kb < X_DIM; kb += 64) {
    const int kk  = (tid & 15) * 4;
    const int tt0 = tid >> 4;
#pragma unroll
    for (int i = 0; i < 4; ++i) {
      const int tt = tt0 + i * 16;
      const f32x4 xv = *(const f32x4*)(x  + (size_t)(t0 + tt) * X_DIM + kb + kk);
      const f32x4 bv = *(const f32x4*)(Bm + (size_t)(h0 + tt) * X_DIM + kb + kk);
#pragma unroll
      for (int q = 0; q < 4; ++q) {
        xs[kk + q][tt] = xv[q];
        bs[kk + q][tt] = bv[q];
      }
    }
    __syncthreads();

#pragma unroll 8
    for (int k = 0; k < 64; ++k) {
      const f32x4 xv = *(const f32x4*)&xs[k][lr * 4];
      const f32x4 bv = *(const f32x4*)&bs[k][lc * 4];
#pragma unroll
      for (int i = 0; i < 4; ++i)
#pragma unroll
        for (int j = 0; j < 4; ++j)
          acc[i][j] = fmaf(xv[i], bv[j], acc[i][j]);
    }
    __syncthreads();
  }

  const f32x4 cv = *(const f32x4*)(c + h0 + lc * 4);
#pragma unroll
  for (int i = 0; i < 4; ++i) {
    f32x4 o;
#pragma unroll
    for (int j = 0; j < 4; ++j) o[j] = acc[i][j] + cv[j];
    *(f32x4*)(out + (size_t)(t0 + lr * 4 + i) * H_DIM + h0 + lc * 4) = o;
  }
}

// ---------------------------------------------------------------------------
// Kernel 2: 256 blocks. Blocks 0-63 = scan workers (r2-proven geometry:
// 4 waves/block, wave owns 4 rows, lane l consumes h[16l..16l+15]; publish
// lanes<32, one instr). Changes vs r2 (22.25 ms):
//  (1) sentinel+speculative-full twin poll in ONE asm block, s_sleep(4)
//      throttled -> ~300cy sampling at ~r2's fabric request rate;
//  (2) C++ full-tag recheck + r2-proven serial-poll fallback on mismatch
//      (covers MALL read reordering / partial publish visibility);
//  (3) __launch_bounds__(256,1): A-fragment stays register-resident
//      (r2/r6's VGPR=60 proved A was being reloaded every step);
//  (4) transposed reduce (r6 HW-proven).
// Skew proof unchanged: publishing t+1 requires full h(t) validated (all 64
// groups, one per lane) -> every wave finished t-1 -> the (slot,tag) being
// overwritten has no remaining readers. Entry/exit vmcnt(0) preserves the
// per-step drain ordering same-dword publishes across slot/tag reuse.
// Blocks 64-255 = DVFS fillers (unchanged, hard-capped).
// ---------------------------------------------------------------------------
__global__ __launch_bounds__(256, 1) void rnn_scan(const float* __restrict__ A_raw,
                                                   float* __restrict__ out,
                                                   u32* __restrict__ ws) {
  const int tid = threadIdx.x;

  if (blockIdx.x >= 64) {
    // ---- filler: keep the DPM governor at high clock ----
    const u32* flag = ws + FLAG_OFF;
    float f0 = 0.f, f1 = 0.f, f2 = 0.f, f3 = 0.f;
    float f4 = 0.f, f5 = 0.f, f6 = 0.f, f7 = 0.f;
    const float m = 1.0000001f, ad = 1e-9f;
    for (int outer = 0; outer < 32768; ++outer) {   // hard cap ~56 ms @2.4GHz
      if (coh_load1(flag) != 0u) break;
      for (int i = 0; i < 256; ++i) {               // ~4096 cyc of VALU burn
        f0 = fmaf(f0, m, ad); f1 = fmaf(f1, m, ad);
        f2 = fmaf(f2, m, ad); f3 = fmaf(f3, m, ad);
        f4 = fmaf(f4, m, ad); f5 = fmaf(f5, m, ad);
        f6 = fmaf(f6, m, ad); f7 = fmaf(f7, m, ad);
      }
    }
    if (f0 + f1 + f2 + f3 + f4 + f5 + f6 + f7 == 123456.789f && tid == 0)
      coh_store1(ws + FLAG_OFF + 1, 1u);            // DCE guard, never true
    return;
  }

  // ---- worker wave (r2 geometry) ----
  const int lane    = tid & 63;
  const int wv      = tid >> 6;
  const int wg      = blockIdx.x;
  const int gw      = wg * 4 + wv;      // global wave id 0..255
  const int rowbase = gw * 4;
  const int r       = lane & 3;
  const int row     = rowbase + r;      // this lane's output row (lanes mod 4)

  // A fragment: a[rr][k] = 0.1*A_raw[rowbase+rr][16*lane+k] + 0.9*(col==row).
  // With launch_bounds(256,1) these 64 floats stay register-resident.
  float a[4][16];
#pragma unroll
  for (int rr = 0; rr < 4; ++rr) {
#pragma unroll
    for (int k4 = 0; k4 < 4; ++k4) {
      const f32x4 v = *(const f32x4*)(A_raw + (size_t)(rowbase + rr) * H_DIM +
                                      lane * 16 + k4 * 4);
#pragma unroll
      for (int q = 0; q < 4; ++q) {
        const int col = lane * 16 + k4 * 4 + q;
        a[rr][k4 * 4 + q] = 0.1f * v[q] + (col == rowbase + rr ? 0.9f : 0.0f);
      }
    }
  }

  u32* hbuf = ws;
  const u32* ppoll0 = hbuf + (size_t)(gw & (NREP - 1)) * REP_U32 + 16 * lane;
  u32* pub = hbuf + (size_t)(lane >> 2) * REP_U32 + rowbase + r;  // lanes<32

  // 2-deep bx prefetch: out[t] rows are only overwritten by THIS wave at
  // step t -> reading out[t+2] at step t is read-before-write, same wave.
  float bx_val = out[(size_t)0 * H_DIM + row];
  float bx_n1  = out[(size_t)1 * H_DIM + row];

  int  dead2   = 1 << 20;     // fallback-loop budget (r2-proven envelope)
  bool timeout = false;

  for (int t = 0; t < T_LEN; ++t) {
    const u32 tag = (u32)(t & 3);
    const u32* p  = ppoll0 + (t & 1) * SLOT_U32;

    u32 sa0, sa1, sa2, sa3, sb0, sb1, sb2, sb3, tmp1, tmp2, tmo, wh;
    u32x4 fa0, fa1, fa2, fa3, fb0, fb1, fb2, fb3;
    u32 sdead;
    asm volatile(
        // entry drain: prior publish/out/bx VMEM retired (per-step invariant)
        "s_waitcnt vmcnt(0)\n\t"
        "s_mov_b32 %[sd], 0x100000\n\t"      // deadman: 2^20 misses (~310ms max)
        "v_mov_b32 %[to], 0\n\t"
        "v_mov_b32 %[wh], 0\n\t"
        ISSUE_SET(xa0, xa1, xa2, xa3, qa0, qa1, qa2, qa3)   // set A (8 VMEM)
        ISSUE_SET(xb0, xb1, xb2, xb3, qb0, qb1, qb2, qb3)   // set B (8 VMEM)
        "Lp%=:\n\t"
        "s_waitcnt vmcnt(8)\n\t"             // older set (A) fully landed
        CHK_SENT(xa0, xa1, xa2, xa3)
        "s_cbranch_vccz Ld%=\n\t"            // all 64 lanes tagged -> accept A
        "s_sub_u32 %[sd], %[sd], 1\n\t"
        "s_cbranch_scc1 Lt%=\n\t"            // borrow -> timeout
        "s_sleep 4\n\t"                      // ~256cy throttle (r6 lesson)
        ISSUE_SET(xa0, xa1, xa2, xa3, qa0, qa1, qa2, qa3)
        "s_waitcnt vmcnt(8)\n\t"             // set B landed
        CHK_SENT(xb0, xb1, xb2, xb3)
        "s_cbranch_vccz Lb%=\n\t"
        "s_sub_u32 %[sd], %[sd], 1\n\t"
        "s_cbranch_scc1 Lt%=\n\t"
        "s_sleep 4\n\t"
        ISSUE_SET(xb0, xb1, xb2, xb3, qb0, qb1, qb2, qb3)
        "s_branch Lp%=\n\t"
        "Lb%=:\n\t"
        "v_mov_b32 %[wh], 1\n\t"
        "s_branch Ld%=\n\t"
        "Lt%=:\n\t"
        "v_mov_b32 %[to], 1\n\t"
        "Ld%=:\n\t"
        "s_waitcnt vmcnt(0)\n\t"             // ALL loads landed before exit
        : [xa0]"=&v"(sa0), [xa1]"=&v"(sa1), [xa2]"=&v"(sa2), [xa3]"=&v"(sa3),
          [xb0]"=&v"(sb0), [xb1]"=&v"(sb1), [xb2]"=&v"(sb2), [xb3]"=&v"(sb3),
          [qa0]"=&v"(fa0), [qa1]"=&v"(fa1), [qa2]"=&v"(fa2), [qa3]"=&v"(fa3),
          [qb0]"=&v"(fb0), [qb1]"=&v"(fb1), [qb2]"=&v"(fb2), [qb3]"=&v"(fb3),
          [t]"=&v"(tmp1), [u]"=&v"(tmp2), [to]"=&v"(tmo), [wh]"=&v"(wh),
          [sd]"=&s"(sdead)
        : [gp]"v"(p), [stag]"s"(tag)
        : "vcc", "scc", "memory");

    // Select the accepted set (all registers landed -> safe to copy in C++).
    u32x4 hA = wh ? fb0 : fa0;
    u32x4 hB = wh ? fb1 : fa1;
    u32x4 hC = wh ? fb2 : fa2;
    u32x4 hD = wh ? fb3 : fa3;

    // Full-tag recheck; fall back to the r2-proven serial poll on mismatch
    // (sentinel pass does NOT imply the full speculative read caught all 16
    // dwords -- MALL may reorder the two requests).
    if (__any(tagchk(hA, hB, hC, hD, tag) != 0u)) {
      for (;;) {
        poll_group(p, hA, hB, hC, hD);
        if (tagchk(hA, hB, hC, hD, tag) == 0u) break;
        if (--dead2 == 0) { timeout = true; break; }
      }
    }
    timeout |= (tmo != 0u);
    if (__any(timeout)) {
      if (lane == 0) coh_store1(ws + FLAG_OFF, 1u);  // fail fast, release fillers
      return;
    }

    // Issue bx(t+2) now; ~2 full step periods to cover HBM latency.
    const int tn2 = (t + 2 < T_LEN) ? t + 2 : t;
    const float bx_n2 = out[(size_t)tn2 * H_DIM + row];

    // Partial dots straight from poll registers (tag bits left in mantissa,
    // rel err <= 2^-22 -- same as proven version).
    const f32x4 f0 = __builtin_bit_cast(f32x4, hA);
    const f32x4 f1 = __builtin_bit_cast(f32x4, hB);
    const f32x4 f2 = __builtin_bit_cast(f32x4, hC);
    const f32x4 f3 = __builtin_bit_cast(f32x4, hD);
    float hv[16];
#pragma unroll
    for (int k = 0; k < 4; ++k) {
      hv[k]      = f0[k];
      hv[4 + k]  = f1[k];
      hv[8 + k]  = f2[k];
      hv[12 + k] = f3[k];
    }

    float ac0 = 0.f, ac1 = 0.f, ac2 = 0.f, ac3 = 0.f;
#pragma unroll
    for (int k = 0; k < 16; ++k) {
      ac0 = fmaf(a[0][k], hv[k], ac0);
      ac1 = fmaf(a[1][k], hv[k], ac1);
      ac2 = fmaf(a[2][k], hv[k], ac2);
      ac3 = fmaf(a[3][k], hv[k], ac3);
    }

    // Transposed reduce [r6 HW-proven]: fold 4 values -> 1 per lane (2 DPP
    // quad_perm steps), then 4 shfl_xor. Lane l ends holding the full
    // 64-lane sum of ac_{l&3} == its own row's dot product.
    const float lo01 = (lane & 1) ? ac1 : ac0;
    const float ot01 = (lane & 1) ? ac0 : ac1;
    const float lo23 = (lane & 1) ? ac3 : ac2;
    const float ot23 = (lane & 1) ? ac2 : ac3;
    const float p01  = lo01 + dpp_xor1(ot01);
    const float p23  = lo23 + dpp_xor1(ot23);
    const float keep = (lane & 2) ? p23 : p01;
    const float give = (lane & 2) ? p01 : p23;
    float x = keep + dpp_xor2(give);
    x += __shfl_xor(x, 4, 64);
    x += __shfl_xor(x, 8, 64);
    x += __shfl_xor(x, 16, 64);
    x += __shfl_xor(x, 32, 64);

    const float v = fast_tanh(x + bx_val);
    bx_val = bx_n1;
    bx_n1  = bx_n2;

    const u32 nt = (u32)((t + 1) & 3);
    if (lane < 4 * NREP) {
      // lanes 0..31: publish to replica lane>>2, row-class lane&3.
      coh_store1(pub + (size_t)((t + 1) & 1) * SLOT_U32,
                 (__float_as_uint(v) & ~3u) | nt);
    } else if (lane < 4 * NREP + 4) {
      // lanes 32..35: clean output write (bx already consumed this step).
      out[(size_t)t * H_DIM + row] = v;
    }
  }

  if (gw == 0 && lane == 0) coh_store1(ws + FLAG_OFF, 1u);  // release fillers
}

// ---------------------------------------------------------------------------
extern "C" void kernel_launch(void* const* d_in, const int* in_sizes, int n_in,
                              void* d_out, int out_size, void* d_ws, size_t ws_size,
                              hipStream_t stream) {
  const float* x    = (const float*)d_in[0];  // (T, X)
  const float* h0   = (const float*)d_in[1];  // (H,)
  const float* Araw = (const float*)d_in[2];  // (H, H)
  const float* B    = (const float*)d_in[3];  // (H, X)
  const float* c    = (const float*)d_in[4];  // (H,)
  float* out = (float*)d_out;                 // (T, H)
  u32* ws    = (u32*)d_ws;                    // 64 KB hbuf + flag dwords

  hinit<<<1, 256, 0, stream>>>(h0, ws);
  dim3 g(T_LEN / 64, H_DIM / 64);
  gemm_bx<<<g, 256, 0, stream>>>(x, B, c, out);
  rnn_scan<<<256, 256, 0, stream>>>(Araw, out, ws);
}

// Round 8
// 25005.244 us; speedup vs baseline: 6.2884x; 3.6540x over previous
//
#include <hip/hip_runtime.h>
#include <cstdint>

#define T_LEN 16384
#define X_DIM 256
#define H_DIM 1024
#define NREP  8                    // h-buffer replicas (slice spreading)
#define SLOT_U32 1024              // col c lives at dword c (linear, proven r2)
#define REP_U32  (2 * SLOT_U32)    // ping-pong slots per replica
#define FLAG_OFF (NREP * REP_U32)  // 16384 dwords = 64 KB

typedef unsigned int u32;
typedef u32   u32x4 __attribute__((ext_vector_type(4)));
typedef float f32x4 __attribute__((ext_vector_type(4)));

// ---------------------------------------------------------------------------
// Device-scope coherent ops. sc0 sc1 -> MALL is the coherence point (per-XCD
// L2s are NOT cross-coherent; r3: sc0-only visibility is eviction-timing-
// dependent). Every published dword self-validates via a 2-bit step tag in
// its mantissa LSBs -> only 4 B atomicity required.
// POLL DOCTRINE (r4-r7 concluded): r2's serial 4x dwordx4 + vmcnt(0) +
// exec-dropout loop is the right poll. Dropout collapses steady-state MALL
// traffic to laggard lanes only; every pipelined/sentinel variant raised
// the request rate and lost 4-7x to fabric queueing. Do not revisit.
// ---------------------------------------------------------------------------
__device__ __forceinline__ void coh_store4(u32* p, u32x4 v) {
  asm volatile("global_store_dwordx4 %0, %1, off sc0 sc1" :: "v"(p), "v"(v) : "memory");
}
__device__ __forceinline__ void coh_store1(u32* p, u32 v) {
  asm volatile("global_store_dword %0, %1, off sc0 sc1" :: "v"(p), "v"(v) : "memory");
}
__device__ __forceinline__ u32 coh_load1(const u32* p) {
  u32 v;
  asm volatile("global_load_dword %0, %1, off sc0 sc1\n\ts_waitcnt vmcnt(0)"
               : "=v"(v) : "v"(p) : "memory");
  return v;
}
// r2-proven poll iteration: 4 dwordx4 + vmcnt(0); values landed at asm exit.
__device__ __forceinline__ void poll_group(const u32* p, u32x4& a, u32x4& b,
                                           u32x4& c, u32x4& d) {
  asm volatile(
      "global_load_dwordx4 %0, %4, off sc0 sc1\n\t"
      "global_load_dwordx4 %1, %4, off offset:16 sc0 sc1\n\t"
      "global_load_dwordx4 %2, %4, off offset:32 sc0 sc1\n\t"
      "global_load_dwordx4 %3, %4, off offset:48 sc0 sc1\n\t"
      "s_waitcnt vmcnt(0)"
      : "=&v"(a), "=&v"(b), "=&v"(c), "=&v"(d) : "v"(p) : "memory");
}

__device__ __forceinline__ float fast_tanh(float x) {
  x = fminf(9.0f, fmaxf(-9.0f, x));
  const float e = __builtin_amdgcn_exp2f(x * 2.8853900817779268f); // 2*log2(e)
  return (e - 1.0f) * __builtin_amdgcn_rcpf(e + 1.0f);
}

// xor1 / xor2 within each quad via DPP quad_perm (pure VALU). [r6/r7 HW-proven]
__device__ __forceinline__ float dpp_xor1(float x) {  // quad_perm [1,0,3,2]
  return __int_as_float(__builtin_amdgcn_update_dpp(0, __float_as_int(x),
                                                    0xB1, 0xF, 0xF, false));
}
__device__ __forceinline__ float dpp_xor2(float x) {  // quad_perm [2,3,0,1]
  return __int_as_float(__builtin_amdgcn_update_dpp(0, __float_as_int(x),
                                                    0x4E, 0xF, 0xF, false));
}

// ---------------------------------------------------------------------------
// Kernel 0: seed slot 0 of every replica with h0 (tag 0) and zero the filler
// done-flag. Poison 0xAAAAAAAA has tag LSBs 0b10, never matching slot0 tags
// {0,2} (overwritten here) nor slot1's first expected tag 1.
// ---------------------------------------------------------------------------
__global__ void hinit(const float* __restrict__ h0, u32* __restrict__ ws) {
  const int i = threadIdx.x;              // 256 threads x 4 cols
  const f32x4 h = *(const f32x4*)(h0 + i * 4);
  u32x4 v;
  v.x = __float_as_uint(h[0]) & ~3u;
  v.y = __float_as_uint(h[1]) & ~3u;
  v.z = __float_as_uint(h[2]) & ~3u;
  v.w = __float_as_uint(h[3]) & ~3u;
  const int idx = i * 4;                  // linear layout, 16 B aligned
#pragma unroll
  for (int rep = 0; rep < NREP; ++rep)
    coh_store4(ws + (size_t)rep * REP_U32 + idx, v);
  if (i < 2) coh_store1(ws + FLAG_OFF + i, 0u);  // done flag + spare
}

// ---------------------------------------------------------------------------
// Kernel 1: Bx_c = x @ B^T + c into d_out. Unchanged (proven).
// ---------------------------------------------------------------------------
__global__ __launch_bounds__(256) void gemm_bx(const float* __restrict__ x,
                                               const float* __restrict__ Bm,
                                               const float* __restrict__ c,
                                               float* __restrict__ out) {
  __shared__ float xs[64][68];
  __shared__ float bs[64][68];

  const int tid = threadIdx.x;
  const int t0  = blockIdx.x * 64;
  const int h0  = blockIdx.y * 64;
  const int lr  = tid >> 4;
  const int lc  = tid & 15;

  float acc[4][4] = {};

  for (int kb = 0; kb < X_DIM; kb += 64) {
    const int kk  = (tid & 15) * 4;
    const int tt0 = tid >> 4;
#pragma unroll
    for (int i = 0; i < 4; ++i) {
      const int tt = tt0 + i * 16;
      const f32x4 xv = *(const f32x4*)(x  + (size_t)(t0 + tt) * X_DIM + kb + kk);
      const f32x4 bv = *(const f32x4*)(Bm + (size_t)(h0 + tt) * X_DIM + kb + kk);
#pragma unroll
      for (int q = 0; q < 4; ++q) {
        xs[kk + q][tt] = xv[q];
        bs[kk + q][tt] = bv[q];
      }
    }
    __syncthreads();

#pragma unroll 8
    for (int k = 0; k < 64; ++k) {
      const f32x4 xv = *(const f32x4*)&xs[k][lr * 4];
      const f32x4 bv = *(const f32x4*)&bs[k][lc * 4];
#pragma unroll
      for (int i = 0; i < 4; ++i)
#pragma unroll
        for (int j = 0; j < 4; ++j)
          acc[i][j] = fmaf(xv[i], bv[j], acc[i][j]);
    }
    __syncthreads();
  }

  const f32x4 cv = *(const f32x4*)(c + h0 + lc * 4);
#pragma unroll
  for (int i = 0; i < 4; ++i) {
    f32x4 o;
#pragma unroll
    for (int j = 0; j < 4; ++j) o[j] = acc[i][j] + cv[j];
    *(f32x4*)(out + (size_t)(t0 + lr * 4 + i) * H_DIM + h0 + lc * 4) = o;
  }
}

// ---------------------------------------------------------------------------
// Kernel 2: 256 blocks. Blocks 0-63 = scan workers -- the r2-proven 22.25 ms
// structure (4 waves/block, wave owns 4 rows, lane l polls h[16l..16l+15]
// from its replica; publish lanes<32, one instr) with three local changes:
//  (1) __launch_bounds__(256,1): unlock VGPR budget (1 block/CU anyway);
//  (2) asm-tie of the 64 A-fragment values: an asm-defined value cannot be
//      rematerialized -> forces the A-fragment register-resident, removing
//      ~16 L1 loads + 64 scale-FMAs from the post-accept critical path
//      (r2/r7's VGPR=60-64 proved A was being recomputed every step);
//  (3) transposed reduce (r6/r7 HW-proven): 2 DPP quad_perm folds + 4
//      shfl_xor instead of 4 full 64-lane reduces.
// Skew proof unchanged: publishing t+1 requires full h(t) validated (all 64
// groups, one per lane) -> every wave finished t-1 -> the (slot,tag) being
// overwritten has no remaining readers. Per-iteration vmcnt(0) in poll_group
// orders same-dword publishes across the 8-step (slot,tag) reuse period.
// Blocks 64-255 = DVFS fillers (unchanged, hard-capped).
// ---------------------------------------------------------------------------
__global__ __launch_bounds__(256, 1) void rnn_scan(const float* __restrict__ A_raw,
                                                   float* __restrict__ out,
                                                   u32* __restrict__ ws) {
  const int tid = threadIdx.x;

  if (blockIdx.x >= 64) {
    // ---- filler: keep the DPM governor at high clock ----
    const u32* flag = ws + FLAG_OFF;
    float f0 = 0.f, f1 = 0.f, f2 = 0.f, f3 = 0.f;
    float f4 = 0.f, f5 = 0.f, f6 = 0.f, f7 = 0.f;
    const float m = 1.0000001f, ad = 1e-9f;
    for (int outer = 0; outer < 32768; ++outer) {   // hard cap ~56 ms @2.4GHz
      if (coh_load1(flag) != 0u) break;
      for (int i = 0; i < 256; ++i) {               // ~4096 cyc of VALU burn
        f0 = fmaf(f0, m, ad); f1 = fmaf(f1, m, ad);
        f2 = fmaf(f2, m, ad); f3 = fmaf(f3, m, ad);
        f4 = fmaf(f4, m, ad); f5 = fmaf(f5, m, ad);
        f6 = fmaf(f6, m, ad); f7 = fmaf(f7, m, ad);
      }
    }
    if (f0 + f1 + f2 + f3 + f4 + f5 + f6 + f7 == 123456.789f && tid == 0)
      coh_store1(ws + FLAG_OFF + 1, 1u);            // DCE guard, never true
    return;
  }

  // ---- worker wave (r2 geometry) ----
  const int lane    = tid & 63;
  const int wv      = tid >> 6;
  const int wg      = blockIdx.x;
  const int gw      = wg * 4 + wv;      // global wave id 0..255
  const int rowbase = gw * 4;
  const int r       = lane & 3;
  const int row     = rowbase + r;      // this lane's output row (lanes mod 4)

  // A fragment: a[rr][k] = 0.1*A_raw[rowbase+rr][16*lane+k] + 0.9*(col==row).
  float a[4][16];
#pragma unroll
  for (int rr = 0; rr < 4; ++rr) {
#pragma unroll
    for (int k4 = 0; k4 < 4; ++k4) {
      const f32x4 v = *(const f32x4*)(A_raw + (size_t)(rowbase + rr) * H_DIM +
                                      lane * 16 + k4 * 4);
#pragma unroll
      for (int q = 0; q < 4; ++q) {
        const int col = lane * 16 + k4 * 4 + q;
        a[rr][k4 * 4 + q] = 0.1f * v[q] + (col == rowbase + rr ? 0.9f : 0.0f);
      }
    }
  }
  // Asm-tie: make each A value asm-defined -> non-rematerializable -> the
  // allocator must keep it in a VGPR for the whole loop (budget 512 at
  // 1 block/CU). Emits zero instructions.
#pragma unroll
  for (int rr = 0; rr < 4; ++rr)
#pragma unroll
    for (int k = 0; k < 16; ++k)
      asm volatile("" : "+v"(a[rr][k]));

  u32* hbuf = ws;
  const u32* ppoll0 = hbuf + (size_t)(gw & (NREP - 1)) * REP_U32 + 16 * lane;
  u32* pub = hbuf + (size_t)(lane >> 2) * REP_U32 + rowbase + r;  // lanes<32

  // 2-deep bx prefetch: out[t] rows are only overwritten by THIS wave at
  // step t -> reading out[t+2] at step t is read-before-write, same wave.
  float bx_val = out[(size_t)0 * H_DIM + row];
  float bx_n1  = out[(size_t)1 * H_DIM + row];

  int  dead    = 1 << 20;   // total poll budget (r2-proven envelope)
  bool timeout = false;

  for (int t = 0; t < T_LEN; ++t) {
    // Poll own group of slot t&1 until all 16 dwords carry tag t&3.
    // Satisfied lanes drop out (exec-masked); wave lockstep re-converges all
    // 64 lanes before the reduce. [r2-proven; see POLL DOCTRINE above]
    const u32 tag = (u32)(t & 3);
    const u32* p  = ppoll0 + (t & 1) * SLOT_U32;
    u32x4 hA, hB, hC, hD;
    for (;;) {
      poll_group(p, hA, hB, hC, hD);
      const u32 m = (hA.x ^ tag) | (hA.y ^ tag) | (hA.z ^ tag) | (hA.w ^ tag)
                  | (hB.x ^ tag) | (hB.y ^ tag) | (hB.z ^ tag) | (hB.w ^ tag)
                  | (hC.x ^ tag) | (hC.y ^ tag) | (hC.z ^ tag) | (hC.w ^ tag)
                  | (hD.x ^ tag) | (hD.y ^ tag) | (hD.z ^ tag) | (hD.w ^ tag);
      if ((m & 3u) == 0u) break;
      if (--dead == 0) { timeout = true; break; }
    }
    if (__any(timeout)) {
      if (lane == 0) coh_store1(ws + FLAG_OFF, 1u);  // fail fast, release fillers
      return;
    }

    // Issue bx(t+2) now; ~2 full step periods to cover HBM latency.
    const int tn2 = (t + 2 < T_LEN) ? t + 2 : t;
    const float bx_n2 = out[(size_t)tn2 * H_DIM + row];

    // Partial dots straight from poll registers (tag bits left in mantissa,
    // rel err <= 2^-22 -- same as proven version).
    const f32x4 f0 = __builtin_bit_cast(f32x4, hA);
    const f32x4 f1 = __builtin_bit_cast(f32x4, hB);
    const f32x4 f2 = __builtin_bit_cast(f32x4, hC);
    const f32x4 f3 = __builtin_bit_cast(f32x4, hD);
    float ac0 = 0.f, ac1 = 0.f, ac2 = 0.f, ac3 = 0.f;
#pragma unroll
    for (int j = 0; j < 4; ++j) {
      ac0 = fmaf(a[0][j], f0[j], ac0); ac1 = fmaf(a[1][j], f0[j], ac1);
      ac2 = fmaf(a[2][j], f0[j], ac2); ac3 = fmaf(a[3][j], f0[j], ac3);
    }
#pragma unroll
    for (int j = 0; j < 4; ++j) {
      ac0 = fmaf(a[0][4 + j], f1[j], ac0); ac1 = fmaf(a[1][4 + j], f1[j], ac1);
      ac2 = fmaf(a[2][4 + j], f1[j], ac2); ac3 = fmaf(a[3][4 + j], f1[j], ac3);
    }
#pragma unroll
    for (int j = 0; j < 4; ++j) {
      ac0 = fmaf(a[0][8 + j], f2[j], ac0); ac1 = fmaf(a[1][8 + j], f2[j], ac1);
      ac2 = fmaf(a[2][8 + j], f2[j], ac2); ac3 = fmaf(a[3][8 + j], f2[j], ac3);
    }
#pragma unroll
    for (int j = 0; j < 4; ++j) {
      ac0 = fmaf(a[0][12 + j], f3[j], ac0); ac1 = fmaf(a[1][12 + j], f3[j], ac1);
      ac2 = fmaf(a[2][12 + j], f3[j], ac2); ac3 = fmaf(a[3][12 + j], f3[j], ac3);
    }

    // Transposed reduce [r6/r7 HW-proven]: fold 4 values -> 1 per lane
    // (2 DPP quad_perm steps + selects), then 4 shfl_xor. Lane l ends
    // holding the full 64-lane sum of ac_{l&3} == its own row's dot.
    const float lo01 = (lane & 1) ? ac1 : ac0;
    const float ot01 = (lane & 1) ? ac0 : ac1;
    const float lo23 = (lane & 1) ? ac3 : ac2;
    const float ot23 = (lane & 1) ? ac2 : ac3;
    const float p01  = lo01 + dpp_xor1(ot01);
    const float p23  = lo23 + dpp_xor1(ot23);
    const float keep = (lane & 2) ? p23 : p01;
    const float give = (lane & 2) ? p01 : p23;
    float x = keep + dpp_xor2(give);
    x += __shfl_xor(x, 4, 64);
    x += __shfl_xor(x, 8, 64);
    x += __shfl_xor(x, 16, 64);
    x += __shfl_xor(x, 32, 64);

    const float v = fast_tanh(x + bx_val);
    bx_val = bx_n1;
    bx_n1  = bx_n2;

    const u32 nt = (u32)((t + 1) & 3);
    if (lane < 4 * NREP) {
      // lanes 0..31: publish to replica lane>>2, row-class lane&3.
      coh_store1(pub + (size_t)((t + 1) & 1) * SLOT_U32,
                 (__float_as_uint(v) & ~3u) | nt);
    } else if (lane < 4 * NREP + 4) {
      // lanes 32..35: clean output write (bx already consumed this step).
      out[(size_t)t * H_DIM + row] = v;
    }
  }

  if (gw == 0 && lane == 0) coh_store1(ws + FLAG_OFF, 1u);  // release fillers
}

// ---------------------------------------------------------------------------
extern "C" void kernel_launch(void* const* d_in, const int* in_sizes, int n_in,
                              void* d_out, int out_size, void* d_ws, size_t ws_size,
                              hipStream_t stream) {
  const float* x    = (const float*)d_in[0];  // (T, X)
  const float* h0   = (const float*)d_in[1];  // (H,)
  const float* Araw = (const float*)d_in[2];  // (H, H)
  const float* B    = (const float*)d_in[3];  // (H, X)
  const float* c    = (const float*)d_in[4];  // (H,)
  float* out = (float*)d_out;                 // (T, H)
  u32* ws    = (u32*)d_ws;                    // 64 KB hbuf + flag dwords

  hinit<<<1, 256, 0, stream>>>(h0, ws);
  dim3 g(T_LEN / 64, H_DIM / 64);
  gemm_bx<<<g, 256, 0, stream>>>(x, B, c, out);
  rnn_scan<<<256, 256, 0, stream>>>(Araw, out, ws);
}